// Round 8
// baseline (771.706 us; speedup 1.0000x reference)
//
#include <hip/hip_runtime.h>

// LocalEncoder on MI355X — round 8: residual-GEMM occupancy fix.
// gemm_res_ln: 64-row tiles, 256 threads, grid 512 -> 2 blocks/CU resident so
// barrier drains overlap across blocks (was 1 block/CU at 512 thr / grid 256).
// copy_ln + cvt_all merged into one prologue dispatch.
// Everything else = round 7: BK=64 XOR-swizzled LDS GEMMs (0 bank conflicts),
// head-major Q/K + permuted f16 V attention, zero-LDS P path, no-max softmax.

#define DIM 256
#define DHEAD 32
#define NWIN 32
#define SEQ 4096
#define TOKENS 32768
#define FFP 704
#define ATT_SCALE_LOG2E 0.25501818642228136f

typedef __attribute__((ext_vector_type(4))) float f32x4;
typedef __attribute__((ext_vector_type(4))) short s16x4;
typedef __attribute__((ext_vector_type(8))) short s16x8;
typedef __attribute__((ext_vector_type(4))) _Float16 f16x4;
typedef __attribute__((ext_vector_type(8))) _Float16 f16x8;

__device__ __forceinline__ short f2bf(float f) {
  unsigned int u = __float_as_uint(f);
  u += 0x7fffu + ((u >> 16) & 1u);
  return (short)(u >> 16);
}

__device__ __forceinline__ float fast_exp2(float x) {
#if __has_builtin(__builtin_amdgcn_exp2f)
  return __builtin_amdgcn_exp2f(x);
#else
  return __expf(x * 0.6931471805599453f);
#endif
}

__device__ __forceinline__ float gelu_exact(float g) {
  return 0.5f * g * (1.0f + erff(g * 0.70710678118654752440f));
}

__device__ __forceinline__ void gl_lds16(const short* g, short* l) {
  __builtin_amdgcn_global_load_lds(
      (const __attribute__((address_space(1))) void*)g,
      (__attribute__((address_space(3))) void*)l, 16, 0, 0);
}

// fragment read from a BK=64 swizzled tile: 16B block g (= kh*4+quad) of `row`
__device__ __forceinline__ s16x8 fragld(const short* lds, int row, int g) {
  return *(const s16x8*)(lds + row * 64 + ((g ^ (row & 7)) << 3));
}

// ---------------- prologue: copy+LN for x0, and all weight casts, one dispatch ----------------
__global__ void __launch_bounds__(256)
prologue(const float* __restrict__ x0, const float* __restrict__ gw,
         const float* __restrict__ bw, float* __restrict__ x, short* __restrict__ xn,
         const float* __restrict__ qkv_w, const float* __restrict__ out_w,
         const float* __restrict__ ff_w1, const float* __restrict__ ff_w2,
         short* __restrict__ wqkv, short* __restrict__ wout,
         short* __restrict__ wff1, short* __restrict__ wff2) {
  if (blockIdx.x < 8192) {
    const int row = blockIdx.x * 4 + (threadIdx.x >> 6);
    const int lane = threadIdx.x & 63;
    const f32x4 v = *(const f32x4*)(x0 + (size_t)row * DIM + lane * 4);
    *(f32x4*)(x + (size_t)row * DIM + lane * 4) = v;
    float s = v[0] + v[1] + v[2] + v[3];
    float s2 = v[0]*v[0] + v[1]*v[1] + v[2]*v[2] + v[3]*v[3];
#pragma unroll
    for (int off = 32; off > 0; off >>= 1) {
      s  += __shfl_xor(s, off, 64);
      s2 += __shfl_xor(s2, off, 64);
    }
    const float mu = s * (1.0f / DIM);
    const float var = s2 * (1.0f / DIM) - mu * mu;
    const float rstd = rsqrtf(var + 1e-5f);
    const f32x4 gv = *(const f32x4*)(gw + lane * 4);
    const f32x4 bv = *(const f32x4*)(bw + lane * 4);
    s16x4 o;
#pragma unroll
    for (int j = 0; j < 4; ++j) o[j] = f2bf((v[j] - mu) * rstd * gv[j] + bv[j]);
    *(s16x4*)(xn + (size_t)row * DIM + lane * 4) = o;
    return;
  }
  int i = (blockIdx.x - 8192) * 256 + threadIdx.x;
  if (i < 786432) { wqkv[i] = f2bf(qkv_w[i]); return; }
  i -= 786432;
  if (i < 262144) { wout[i] = f2bf(out_w[i]); return; }
  i -= 262144;
  if (i < 1441792) {
    const int c = i & 255;
    const int rl = i >> 8;
    const int l = rl / 1408;
    const int r = rl - l * 1408;
    const int half = r / FFP;
    const int rr = r - half * FFP;
    const float v = (rr < 682) ? ff_w1[((size_t)(l * 1364 + half * 682 + rr)) * 256 + c] : 0.0f;
    wff1[i] = f2bf(v);
    return;
  }
  i -= 1441792;
  if (i < 720896) {
    const int c = i % FFP;
    const int t = i / FFP;
    const float v = (c < 682) ? ff_w2[(size_t)t * 682 + c] : 0.0f;
    wff2[i] = f2bf(v);
  }
}

// -------- Residual GEMM + fused next-LN: A[M,K] x W[256,K]; x += A.W^T; xn = LN(x) --------
// 256 threads, 4 waves; block tile 64 x 256 (full row); grid 512 -> 2 blocks/CU.
template<int K, bool DO_LN>
__global__ void __launch_bounds__(256)
gemm_res_ln(const short* __restrict__ A, const short* __restrict__ W,
            float* __restrict__ x, const float* __restrict__ lng,
            const float* __restrict__ lnb, short* __restrict__ xn) {
  __shared__ short As[64 * 64];    // 8 KB
  __shared__ short Bs[256 * 64];   // 32 KB
  const int tid = threadIdx.x;
  const int lane = tid & 63;
  const int w = tid >> 6;              // 0..3
  const int ln16 = lane & 15;
  const int quad = lane >> 4;
  const int m_blk = blockIdx.x * 64;
  const int n0w = w * 64;
  const int srow = lane >> 3;          // 0..7
  const int swz = (lane & 7) ^ srow;   // permuted source col-block

  // 40 staging groups of 8 rows: 0..7 = A, 8..39 = B. Wave w: grp = w + i*4.
  const short* sg[10];
  short* dg[10];
#pragma unroll
  for (int i = 0; i < 10; ++i) {
    const int grp = w + i * 4;
    if (grp < 8) {
      sg[i] = A + (size_t)(m_blk + grp * 8 + srow) * K + swz * 8;
      dg[i] = As + grp * 512;
    } else {
      const int gb = grp - 8;
      sg[i] = W + (size_t)(gb * 8 + srow) * K + swz * 8;
      dg[i] = Bs + gb * 512;
    }
  }

  f32x4 acc[4][4] = {};
  for (int kb = 0; kb < K; kb += 64) {
#pragma unroll
    for (int i = 0; i < 10; ++i) gl_lds16(sg[i] + kb, dg[i]);
    __syncthreads();
    s16x8 af[2][4], bf[2][4];
#pragma unroll
    for (int kh = 0; kh < 2; ++kh) {
#pragma unroll
      for (int mt = 0; mt < 4; ++mt)
        af[kh][mt] = fragld(As, mt * 16 + ln16, kh * 4 + quad);
#pragma unroll
      for (int nt = 0; nt < 4; ++nt)
        bf[kh][nt] = fragld(Bs, n0w + nt * 16 + ln16, kh * 4 + quad);
    }
#pragma unroll
    for (int kh = 0; kh < 2; ++kh)
#pragma unroll
      for (int mt = 0; mt < 4; ++mt)
#pragma unroll
        for (int nt = 0; nt < 4; ++nt)
          acc[mt][nt] = __builtin_amdgcn_mfma_f32_16x16x32_bf16(af[kh][mt], bf[kh][nt], acc[mt][nt], 0, 0, 0);
    __syncthreads();
  }

  // residual add; keep new x values in acc
#pragma unroll
  for (int mt = 0; mt < 4; ++mt)
#pragma unroll
    for (int nt = 0; nt < 4; ++nt)
#pragma unroll
      for (int r = 0; r < 4; ++r) {
        const size_t idx = (size_t)(m_blk + mt * 16 + quad * 4 + r) * DIM
                           + n0w + nt * 16 + ln16;
        const float v = x[idx] + acc[mt][nt][r];
        acc[mt][nt][r] = v;
        x[idx] = v;
      }

  if (DO_LN) {
    float2* red = (float2*)As;   // reuse As (2 KB needed); safe: k-loop ended w/ barrier
#pragma unroll
    for (int mt = 0; mt < 4; ++mt)
#pragma unroll
      for (int r = 0; r < 4; ++r) {
        float s = 0.f, s2 = 0.f;
#pragma unroll
        for (int nt = 0; nt < 4; ++nt) {
          const float v = acc[mt][nt][r];
          s += v; s2 += v * v;
        }
#pragma unroll
        for (int off = 1; off < 16; off <<= 1) {
          s  += __shfl_xor(s, off, 64);
          s2 += __shfl_xor(s2, off, 64);
        }
        if (ln16 == 0)
          red[(mt * 16 + quad * 4 + r) * 4 + w] = float2{s, s2};
      }
    __syncthreads();

    float gv[4], bv[4];
#pragma unroll
    for (int nt = 0; nt < 4; ++nt) {
      gv[nt] = lng[n0w + nt * 16 + ln16];
      bv[nt] = lnb[n0w + nt * 16 + ln16];
    }
#pragma unroll
    for (int mt = 0; mt < 4; ++mt)
#pragma unroll
      for (int r = 0; r < 4; ++r) {
        const int row = mt * 16 + quad * 4 + r;
        const float2 t0 = red[row * 4 + 0];
        const float2 t1 = red[row * 4 + 1];
        const float2 t2 = red[row * 4 + 2];
        const float2 t3 = red[row * 4 + 3];
        const float s  = (t0.x + t1.x) + (t2.x + t3.x);
        const float s2 = (t0.y + t1.y) + (t2.y + t3.y);
        const float mu = s * (1.0f / DIM);
        const float var = s2 * (1.0f / DIM) - mu * mu;
        const float rstd = rsqrtf(var + 1e-5f);
#pragma unroll
        for (int nt = 0; nt < 4; ++nt)
          xn[(size_t)(m_blk + row) * DIM + n0w + nt * 16 + ln16] =
              f2bf((acc[mt][nt][r] - mu) * rstd * gv[nt] + bv[nt]);
      }
  }
}

// -------- QKV GEMM (BK=64 swizzled): Q,K -> head-major; V -> permuted vp f16 --------
__global__ void __launch_bounds__(256)
gemm_qkv(const short* __restrict__ A, const short* __restrict__ W,
         short* __restrict__ qh, short* __restrict__ kh_, _Float16* __restrict__ vp) {
  __shared__ short As[128 * 64];
  __shared__ short Bs[128 * 64];
  const int tid = threadIdx.x;
  const int lane = tid & 63;
  const int w = tid >> 6;
  const int ln16 = lane & 15;
  const int quad = lane >> 4;
  const int m_blk = blockIdx.x * 128;
  const int n_blk = blockIdx.y * 128;
  const int m0w = (w & 1) * 64;
  const int n0w = (w >> 1) * 64;
  const int srow = lane >> 3;
  const int swz = (lane & 7) ^ srow;

  const short* sg[8];
  short* dg[8];
#pragma unroll
  for (int i = 0; i < 8; ++i) {
    const int grp = w + i * 4;
    if (grp < 16) {
      sg[i] = A + (size_t)(m_blk + grp * 8 + srow) * DIM + swz * 8;
      dg[i] = As + grp * 512;
    } else {
      const int gb = grp - 16;
      sg[i] = W + (size_t)(n_blk + gb * 8 + srow) * DIM + swz * 8;
      dg[i] = Bs + gb * 512;
    }
  }

  f32x4 acc[4][4] = {};
  for (int kb = 0; kb < DIM; kb += 64) {
#pragma unroll
    for (int i = 0; i < 8; ++i) gl_lds16(sg[i] + kb, dg[i]);
    __syncthreads();
    s16x8 af[2][4], bf[2][4];
#pragma unroll
    for (int kh = 0; kh < 2; ++kh) {
#pragma unroll
      for (int mt = 0; mt < 4; ++mt)
        af[kh][mt] = fragld(As, m0w + mt * 16 + ln16, kh * 4 + quad);
#pragma unroll
      for (int nt = 0; nt < 4; ++nt)
        bf[kh][nt] = fragld(Bs, n0w + nt * 16 + ln16, kh * 4 + quad);
    }
#pragma unroll
    for (int kh = 0; kh < 2; ++kh)
#pragma unroll
      for (int mt = 0; mt < 4; ++mt)
#pragma unroll
        for (int nt = 0; nt < 4; ++nt)
          acc[mt][nt] = __builtin_amdgcn_mfma_f32_16x16x32_bf16(af[kh][mt], bf[kh][nt], acc[mt][nt], 0, 0, 0);
    __syncthreads();
  }

#pragma unroll
  for (int mt = 0; mt < 4; ++mt) {
    const int m = m_blk + m0w + mt * 16 + quad * 4;   // global token, 4 consecutive
    const int bb = m >> 12;
    const int n = m & 4095;
#pragma unroll
    for (int nt = 0; nt < 4; ++nt) {
      const int f = n_blk + n0w + nt * 16;
      if (f < 512) {
        const int ff = f & 255;
        short* dst = (f < 256 ? qh : kh_)
                     + ((size_t)(bb * 8 + (ff >> 5)) * SEQ + n) * 32 + (ff & 16) + ln16;
#pragma unroll
        for (int r = 0; r < 4; ++r) dst[r * 32] = f2bf(acc[mt][nt][r]);
      } else {
        const int ff = f - 512;
        const int h = ff >> 5;
        const int d = (ff & 16) + ln16;
        const int within = n & 31;
        const int pos = (n & ~31) + ((within & 12) << 1) + ((within >> 4) << 2);
        f16x4 o;
#pragma unroll
        for (int r = 0; r < 4; ++r) o[r] = (_Float16)acc[mt][nt][r];
        *(f16x4*)(vp + ((size_t)(bb * 8 + h) * 32 + d) * SEQ + pos) = o;
      }
    }
  }
}

// -------- FF1 GEMM + fused exact GEGLU (BK=64 swizzled): 128x64 of a AND g --------
__global__ void __launch_bounds__(256)
gemm_geglu128(const short* __restrict__ A, const short* __restrict__ W,
              short* __restrict__ y) {
  __shared__ short As[128 * 64];
  __shared__ short Bs[128 * 64];      // rows 0-63: a-half, 64-127: g-half
  const int tid = threadIdx.x;
  const int lane = tid & 63;
  const int w = tid >> 6;
  const int ln16 = lane & 15;
  const int quad = lane >> 4;
  const int m_blk = blockIdx.x * 128;
  const int n0 = blockIdx.y * 64;
  const int m0w = (w & 1) * 64;
  const int n0w = (w >> 1) * 32;
  const int srow = lane >> 3;
  const int swz = (lane & 7) ^ srow;

  const short* sg[8];
  short* dg[8];
#pragma unroll
  for (int i = 0; i < 8; ++i) {
    const int grp = w + i * 4;
    if (grp < 16) {
      sg[i] = A + (size_t)(m_blk + grp * 8 + srow) * DIM + swz * 8;
      dg[i] = As + grp * 512;
    } else {
      const int gb = grp - 16;
      const int half = gb >> 3;
      sg[i] = W + (size_t)(half * FFP + n0 + (gb & 7) * 8 + srow) * DIM + swz * 8;
      dg[i] = Bs + gb * 512;
    }
  }

  f32x4 acc[2][4][2] = {};
  for (int kb = 0; kb < DIM; kb += 64) {
#pragma unroll
    for (int i = 0; i < 8; ++i) gl_lds16(sg[i] + kb, dg[i]);
    __syncthreads();
    s16x8 af[2][4], ba[2][2], bg[2][2];
#pragma unroll
    for (int kh = 0; kh < 2; ++kh) {
#pragma unroll
      for (int mt = 0; mt < 4; ++mt)
        af[kh][mt] = fragld(As, m0w + mt * 16 + ln16, kh * 4 + quad);
#pragma unroll
      for (int nt = 0; nt < 2; ++nt) {
        ba[kh][nt] = fragld(Bs, n0w + nt * 16 + ln16, kh * 4 + quad);
        bg[kh][nt] = fragld(Bs, 64 + n0w + nt * 16 + ln16, kh * 4 + quad);
      }
    }
#pragma unroll
    for (int kh = 0; kh < 2; ++kh)
#pragma unroll
      for (int mt = 0; mt < 4; ++mt)
#pragma unroll
        for (int nt = 0; nt < 2; ++nt) {
          acc[0][mt][nt] = __builtin_amdgcn_mfma_f32_16x16x32_bf16(af[kh][mt], ba[kh][nt], acc[0][mt][nt], 0, 0, 0);
          acc[1][mt][nt] = __builtin_amdgcn_mfma_f32_16x16x32_bf16(af[kh][mt], bg[kh][nt], acc[1][mt][nt], 0, 0, 0);
        }
    __syncthreads();
  }

#pragma unroll
  for (int mt = 0; mt < 4; ++mt)
#pragma unroll
    for (int nt = 0; nt < 2; ++nt)
#pragma unroll
      for (int r = 0; r < 4; ++r)
        y[(size_t)(m_blk + m0w + mt * 16 + quad * 4 + r) * FFP
          + n0 + n0w + nt * 16 + ln16] =
            f2bf(acc[0][mt][nt][r] * gelu_exact(acc[1][mt][nt][r]));
}

// ---------------- Local attention: wave = half-window (4 q-tiles), prefetched ----------------
__global__ void __launch_bounds__(256)
attn_kernel(const short* __restrict__ qh, const short* __restrict__ kh,
            const _Float16* __restrict__ vp, short* __restrict__ out) {
  const int blk = blockIdx.x;              // 1024 blocks
  const int lane = threadIdx.x & 63;
  const int wid = threadIdx.x >> 6;
  const int ln16 = lane & 15;
  const int quad = lane >> 4;

  const int w = (blk & 15) * 2 + (wid >> 1);
  const int h = (blk >> 4) & 7;
  const int b = blk >> 7;
  const int plane = b * 8 + h;
  const int tok0 = w * 128 + (wid & 1) * 64;
  const int ktok = w * 128 - 128;
  const int c0 = (w == 0) ? 4 : 0;
  const int c1 = (w == NWIN - 1) ? 8 : 12;

  const short* qp = qh + ((size_t)plane * SEQ + tok0) * 32;
  s16x8 qf[4];
#pragma unroll
  for (int qi = 0; qi < 4; ++qi)
    qf[qi] = *(const s16x8*)(qp + (qi * 16 + ln16) * 32 + quad * 8);

  const short* kp = kh + ((size_t)plane * SEQ + ktok) * 32;
  const _Float16* vb = vp + ((size_t)plane * 32 + ln16) * SEQ + ktok;

  float lsum[4] = {0.f, 0.f, 0.f, 0.f};
  f32x4 ot[4][2] = {};

  s16x8 kc0 = *(const s16x8*)(kp + (c0 * 32 + ln16) * 32 + quad * 8);
  s16x8 kc1 = *(const s16x8*)(kp + (c0 * 32 + 16 + ln16) * 32 + quad * 8);
  f16x8 vc0 = *(const f16x8*)(vb + c0 * 32 + quad * 8);
  f16x8 vc1 = *(const f16x8*)(vb + (size_t)16 * SEQ + c0 * 32 + quad * 8);

  for (int c = c0; c < c1; ++c) {
    const int cn = (c + 1 < c1) ? c + 1 : c;
    s16x8 kn0 = *(const s16x8*)(kp + (cn * 32 + ln16) * 32 + quad * 8);
    s16x8 kn1 = *(const s16x8*)(kp + (cn * 32 + 16 + ln16) * 32 + quad * 8);
    f16x8 vn0 = *(const f16x8*)(vb + cn * 32 + quad * 8);
    f16x8 vn1 = *(const f16x8*)(vb + (size_t)16 * SEQ + cn * 32 + quad * 8);

    const f16x4 v00 = __builtin_shufflevector(vc0, vc0, 0, 1, 2, 3);
    const f16x4 v10 = __builtin_shufflevector(vc0, vc0, 4, 5, 6, 7);
    const f16x4 v01 = __builtin_shufflevector(vc1, vc1, 0, 1, 2, 3);
    const f16x4 v11 = __builtin_shufflevector(vc1, vc1, 4, 5, 6, 7);

#pragma unroll
    for (int qi = 0; qi < 4; ++qi) {
      const f32x4 z = {0.f, 0.f, 0.f, 0.f};
      f32x4 st0 = __builtin_amdgcn_mfma_f32_16x16x32_bf16(kc0, qf[qi], z, 0, 0, 0);
      f32x4 st1 = __builtin_amdgcn_mfma_f32_16x16x32_bf16(kc1, qf[qi], z, 0, 0, 0);
      float p[8];
#pragma unroll
      for (int r = 0; r < 4; ++r) {
        p[r]     = fast_exp2(st0[r] * ATT_SCALE_LOG2E);
        p[4 + r] = fast_exp2(st1[r] * ATT_SCALE_LOG2E);
      }
      lsum[qi] += ((p[0] + p[1]) + (p[2] + p[3])) + ((p[4] + p[5]) + (p[6] + p[7]));
      f16x4 pa, pb;
#pragma unroll
      for (int r = 0; r < 4; ++r) { pa[r] = (_Float16)p[r]; pb[r] = (_Float16)p[4 + r]; }
      ot[qi][0] = __builtin_amdgcn_mfma_f32_16x16x16f16(pa, v00, ot[qi][0], 0, 0, 0);
      ot[qi][1] = __builtin_amdgcn_mfma_f32_16x16x16f16(pa, v01, ot[qi][1], 0, 0, 0);
      ot[qi][0] = __builtin_amdgcn_mfma_f32_16x16x16f16(pb, v10, ot[qi][0], 0, 0, 0);
      ot[qi][1] = __builtin_amdgcn_mfma_f32_16x16x16f16(pb, v11, ot[qi][1], 0, 0, 0);
    }
    kc0 = kn0; kc1 = kn1; vc0 = vn0; vc1 = vn1;
  }

#pragma unroll
  for (int qi = 0; qi < 4; ++qi) {
    float l = lsum[qi];
    l += __shfl_xor(l, 16, 64);
    l += __shfl_xor(l, 32, 64);
    const float inv = 1.0f / l;
#pragma unroll
    for (int dt = 0; dt < 2; ++dt)
#pragma unroll
      for (int r = 0; r < 4; ++r)
        out[(size_t)(b * SEQ + tok0 + qi * 16 + quad * 4 + r) * DIM
            + h * DHEAD + dt * 16 + ln16] = f2bf(ot[qi][dt][r] * inv);
  }
}

// ---------------- driver ----------------
extern "C" void kernel_launch(void* const* d_in, const int* in_sizes, int n_in,
                              void* d_out, int out_size, void* d_ws, size_t ws_size,
                              hipStream_t stream) {
  const float* x0    = (const float*)d_in[0];
  const float* ln1_g = (const float*)d_in[2];
  const float* ln1_b = (const float*)d_in[3];
  const float* qkv_w = (const float*)d_in[4];
  const float* out_w = (const float*)d_in[5];
  const float* ln2_g = (const float*)d_in[6];
  const float* ln2_b = (const float*)d_in[7];
  const float* ff_w1 = (const float*)d_in[8];
  const float* ff_w2 = (const float*)d_in[9];
  float* x = (float*)d_out;

  char* ws = (char*)d_ws;
  short* wqkv = (short*)(ws);                    //  4*768*256 bf16
  short* wout = (short*)(ws + 1572864);          //  4*256*256
  short* wff1 = (short*)(ws + 2097152);          //  4*1408*256
  short* wff2 = (short*)(ws + 4980736);          //  4*256*704
  short* xn   = (short*)(ws + 6422528);          //  32768*256 (LN out / attn out)
  short*    qhb = (short*)(ws + 23199744);                 // 16.8MB qkv->attn
  short*    khb = (short*)(ws + 23199744 + 16777216);      // 16.8MB qkv->attn
  _Float16* vpb = (_Float16*)(ws + 23199744 + 33554432);   // 16.8MB qkv->attn
  short*    yb  = (short*)(ws + 23199744);                 // 46.1MB geglu->ff2 (disjoint lifetime)

  prologue<<<20736, 256, 0, stream>>>(x0, ln1_g, ln1_b, x, xn,
                                      qkv_w, out_w, ff_w1, ff_w2,
                                      wqkv, wout, wff1, wff2);

  for (int l = 0; l < 4; ++l) {
    gemm_qkv<<<dim3(256, 6), 256, 0, stream>>>(
        xn, wqkv + (size_t)l * 768 * DIM, qhb, khb, vpb);
    attn_kernel<<<1024, 256, 0, stream>>>(qhb, khb, vpb, xn);
    gemm_res_ln<256, true><<<512, 256, 0, stream>>>(
        xn, wout + (size_t)l * DIM * DIM, x,
        ln2_g + l * DIM, ln2_b + l * DIM, xn);
    gemm_geglu128<<<dim3(256, 11), 256, 0, stream>>>(
        xn, wff1 + (size_t)l * 2 * FFP * DIM, yb);
    if (l < 3)
      gemm_res_ln<FFP, true><<<512, 256, 0, stream>>>(
          yb, wff2 + (size_t)l * DIM * FFP, x,
          ln1_g + (l + 1) * DIM, ln1_b + (l + 1) * DIM, xn);
    else
      gemm_res_ln<FFP, false><<<512, 256, 0, stream>>>(
          yb, wff2 + (size_t)l * DIM * FFP, x, nullptr, nullptr, nullptr);
  }
}